// Round 11
// baseline (431.122 us; speedup 1.0000x reference)
//
#include <hip/hip_runtime.h>

typedef unsigned short u16;
typedef unsigned int u32;
typedef unsigned long long u64;
typedef __bf16 bf16x8 __attribute__((ext_vector_type(8)));
typedef float f32x4 __attribute__((ext_vector_type(4)));
typedef float f32x16 __attribute__((ext_vector_type(16)));
typedef u32 u32x4 __attribute__((ext_vector_type(4)));

#define DEV static __device__ __forceinline__

constexpr int B_ = 2, L_ = 2048, H_ = 2048;
constexpr int NH_ = 16, HD_ = 128, RD_ = 64;
constexpr int QR_ = 768, KVR_ = 512;
constexpr int BL_ = B_ * L_;          // 4096 tokens
constexpr int QKD_ = HD_ + RD_;       // 192
constexpr int QKS_ = NH_ * QKD_;      // 3072
constexpr int NHHD_ = NH_ * HD_;      // 2048
constexpr int ROWS_ = B_ * NH_ * L_;  // 65536 partial rows per split
constexpr float SCALE2 = 0.07216878364870322f * 1.4426950408889634f;  // 1/sqrt(192)*log2(e)

DEV u16 f2bf(float f) {            // native RNE cast; compiler fuses pairs into v_cvt_pk_bf16_f32
    __bf16 h = (__bf16)f;
    return __builtin_bit_cast(u16, h);
}
DEV float bf2f(u16 h) {
    u32 u = ((u32)h) << 16;
    return __builtin_bit_cast(float, u);
}
DEV u32 pk2(float lo, float hi) { return (u32)f2bf(lo) | ((u32)f2bf(hi) << 16); }
DEV bf16x8 ld8(const u16* p) { return __builtin_bit_cast(bf16x8, *(const u32x4*)p); }
DEV f32x4 mfma16(bf16x8 a, bf16x8 b, f32x4 c) {
    return __builtin_amdgcn_mfma_f32_16x16x32_bf16(a, b, c, 0, 0, 0);
}
DEV f32x16 mfma32(bf16x8 a, bf16x8 b, f32x16 c) {
    return __builtin_amdgcn_mfma_f32_32x32x16_bf16(a, b, c, 0, 0, 0);
}
DEV void gload16(const void* g, void* l) {
    __builtin_amdgcn_global_load_lds((const __attribute__((address_space(1))) void*)g,
                                     (__attribute__((address_space(3))) void*)l, 16, 0, 0);
}
// half-exchange: after plswap(a,b): a = {a_lo | b_lo}, b = {a_hi | b_hi} across lane halves.
// Routing HW-verified R4/R10 (passed with identical surrounding pack code).
DEV void plswap(u32& a, u32& b) {
    asm("v_permlane32_swap_b32 %0, %1" : "+v"(a), "+v"(b));
}

// ---------------- elementwise cast: f32 -> bf16, 4 elems/thread ----------------
__global__ __launch_bounds__(256) void cast_bf16_kernel(const float* __restrict__ src,
                                                        u16* __restrict__ dst, int n4) {
    int i = blockIdx.x * 256 + threadIdx.x;
    if (i >= n4) return;
    float4 v = ((const float4*)src)[i];
    u64 pk = (u64)f2bf(v.x) | ((u64)f2bf(v.y) << 16) | ((u64)f2bf(v.z) << 32) | ((u64)f2bf(v.w) << 48);
    ((u64*)dst)[i] = pk;
}

// ------------- fused cast+transpose of ALL 8 weights in one dispatch -------------
__global__ __launch_bounds__(256) void transpose_all(
    const float* __restrict__ s0, const float* __restrict__ s1, const float* __restrict__ s2,
    const float* __restrict__ s3, const float* __restrict__ s4, const float* __restrict__ s5,
    const float* __restrict__ s6, const float* __restrict__ s7,
    u16* __restrict__ Wdn, u16* __restrict__ Wupq, u16* __restrict__ Wupkv, u16* __restrict__ Wo_t) {
    int t = blockIdx.x;
    const float* src; u16* dst; int K, N, nx;
    if (t < 1536)       {            src = s0; dst = Wdn;                          K = 2048; N = 768;  nx = 24; }
    else if (t < 2560)  { t -= 1536; src = s1; dst = Wdn + (size_t)768 * 2048;     K = 2048; N = 512;  nx = 16; }
    else if (t < 2816)  { t -= 2560; src = s2; dst = Wdn + (size_t)1280 * 2048;    K = 2048; N = 64;   nx = 4;  }
    else if (t < 4352)  { t -= 2816; src = s3; dst = Wupq;                         K = 768;  N = 2048; nx = 64; }
    else if (t < 5120)  { t -= 4352; src = s4; dst = Wupq + (size_t)2048 * 768;    K = 768;  N = 1024; nx = 32; }
    else if (t < 6144)  { t -= 5120; src = s5; dst = Wupkv;                        K = 512;  N = 2048; nx = 64; }
    else if (t < 7168)  { t -= 6144; src = s6; dst = Wupkv + (size_t)2048 * 512;   K = 512;  N = 2048; nx = 64; }
    else                { t -= 7168; src = s7; dst = Wo_t;                         K = 2048; N = 2048; nx = 64; }
    const int n0 = (t % nx) * 32, k0 = (t / nx) * 32;

    __shared__ float tile[32][33];
    int tx = threadIdx.x & 31, ty = threadIdx.x >> 5;  // 32 x 8
#pragma unroll
    for (int i = 0; i < 4; ++i) {
        int kk = ty + i * 8;
        int n = n0 + tx;
        tile[kk][tx] = (n < N) ? src[(size_t)(k0 + kk) * N + n] : 0.f;
    }
    __syncthreads();
#pragma unroll
    for (int i = 0; i < 4; ++i) {
        int nn = ty + i * 8;
        dst[(size_t)(n0 + nn) * K + k0 + tx] = f2bf(tile[tx][nn]);
    }
}

// ------------- RoPE cos/sin table: tab[pos*32+i] = {cos, sin}(pos * 10000^(-i/32)) -------------
__global__ __launch_bounds__(256) void build_rope_tab(float2* __restrict__ tab) {
    int idx = blockIdx.x * 256 + threadIdx.x;  // 2048*32
    int pos = idx >> 5, i = idx & 31;
    float freq = exp2f((float)i * (-13.287712379549449f / 32.f));
    float ang = (float)pos * freq;
    tab[idx] = make_float2(cosf(ang), sinf(ang));
}

// ---------------- GEMM: C = A(M x K, lda) * Bt(N x K)^T, BK=64, global_load_lds staging ----------------
// XCD-band swizzle (R8-confirmed fid%8 round-robin).
// EPI: 0 = bf16 C, 1 = f32 C, 2 = QPACK, 3 = KVPACK.
template <int EPI>
__global__ __launch_bounds__(256, 2) void gemm_bt(const u16* __restrict__ A, int lda,
                                                  const u16* __restrict__ Bt,
                                                  void* __restrict__ Cv, void* __restrict__ Cv2,
                                                  int ldc, int K, const float2* __restrict__ tab) {
    __shared__ u16 As[128 * 64];
    __shared__ u16 Bs[128 * 64];
    const int tid = threadIdx.x;
    const int l = tid & 63, w = tid >> 6;
    const int l15 = l & 15, g = l >> 4;
    const int wr = w >> 1, wc = w & 1;
    const int NX = gridDim.x;
    const int fid = blockIdx.x + NX * blockIdx.y;
    const int G = (NX * gridDim.y) >> 3;              // blocks per XCD (grid divisible by 8)
    const int lin = (fid & 7) * G + (fid >> 3);       // xcd-contiguous row-major tile index
    const int bm = (lin / NX) * 128, bn = (lin % NX) * 128;

    const f32x4 zero = {0.f, 0.f, 0.f, 0.f};
    f32x4 acc[4][4];
#pragma unroll
    for (int m = 0; m < 4; ++m)
#pragma unroll
        for (int n = 0; n < 4; ++n) acc[m][n] = zero;

    int aoff[4], boff[4];
#pragma unroll
    for (int j = 0; j < 4; ++j) {
        int chunk = j * 256 + tid;
        int row = chunk >> 3, gr = chunk & 7;
        aoff[j] = row * lda + gr * 8;
        boff[j] = row * K + gr * 8;
    }
    const u16* Ab = A + (size_t)bm * lda;
    const u16* Bb = Bt + (size_t)bn * K;

    const int nK = K / 64;
    for (int kt = 0; kt < nK; ++kt) {
        const int ko = kt * 64;
        __syncthreads();
#pragma unroll
        for (int j = 0; j < 4; ++j) gload16(Ab + ko + aoff[j], As + j * 2048 + w * 512);
#pragma unroll
        for (int j = 0; j < 4; ++j) gload16(Bb + ko + boff[j], Bs + j * 2048 + w * 512);
        __syncthreads();
#pragma unroll
        for (int kk = 0; kk < 2; ++kk) {
            bf16x8 af[4], bfr[4];
#pragma unroll
            for (int m = 0; m < 4; ++m)
                af[m] = ld8(As + (wr * 64 + m * 16 + l15) * 64 + kk * 32 + g * 8);
#pragma unroll
            for (int n = 0; n < 4; ++n)
                bfr[n] = ld8(Bs + (wc * 64 + n * 16 + l15) * 64 + kk * 32 + g * 8);
#pragma unroll
            for (int m = 0; m < 4; ++m)
#pragma unroll
                for (int n = 0; n < 4; ++n) acc[m][n] = mfma16(af[m], bfr[n], acc[m][n]);
        }
    }

    // ---- epilogues ----
    if constexpr (EPI == 0 || EPI == 1) {
#pragma unroll
        for (int m = 0; m < 4; ++m)
#pragma unroll
            for (int n = 0; n < 4; ++n)
#pragma unroll
                for (int r = 0; r < 4; ++r) {
                    int row = bm + wr * 64 + m * 16 + g * 4 + r;
                    int col = bn + wc * 64 + n * 16 + l15;
                    if (EPI == 1)
                        ((float*)Cv)[(size_t)row * ldc + col] = acc[m][n][r];
                    else
                        ((u16*)Cv)[(size_t)row * ldc + col] = f2bf(acc[m][n][r]);
                }
    }
    if constexpr (EPI == 2) {  // QPACK: N = [2048 q_content | 1024 q_rope]; all outputs * SCALE2
        const int base = bn + wc * 64;
        u16* qb = (u16*)Cv;
        if (base < 2048) {
            const int h = base >> 7, dbase = base & 127;
#pragma unroll
            for (int m = 0; m < 4; ++m)
#pragma unroll
                for (int n = 0; n < 4; ++n)
#pragma unroll
                    for (int r = 0; r < 4; ++r) {
                        int token = bm + wr * 64 + m * 16 + g * 4 + r;
                        qb[(size_t)token * QKS_ + h * QKD_ + dbase + n * 16 + l15] =
                            f2bf(acc[m][n][r] * SCALE2);
                    }
        } else {
            const int h = (base - 2048) >> 6;
#pragma unroll
            for (int m = 0; m < 4; ++m)
#pragma unroll
                for (int r = 0; r < 4; ++r) {
                    const int token = bm + wr * 64 + m * 16 + g * 4 + r;
                    const int pos = token & (L_ - 1);
                    u16* bp = qb + (size_t)token * QKS_ + h * QKD_ + HD_;
#pragma unroll
                    for (int n = 0; n < 2; ++n) {
                        const int i = n * 16 + l15;
                        float2 cs = tab[pos * 32 + i];
                        float x1 = acc[m][n][r], x2 = acc[m][n + 2][r];
                        bp[i] = f2bf((x1 * cs.x - x2 * cs.y) * SCALE2);
                        bp[i + 32] = f2bf((x2 * cs.x + x1 * cs.y) * SCALE2);
                    }
                }
        }
    }
    if constexpr (EPI == 3) {  // KVPACK: N = [2048 k_content | 2048 v]
        const int base = bn + wc * 64;
        if (base < 2048) {
            u16* kb = (u16*)Cv;
            const int h = base >> 7, dbase = base & 127;
#pragma unroll
            for (int m = 0; m < 4; ++m)
#pragma unroll
                for (int n = 0; n < 4; ++n)
#pragma unroll
                    for (int r = 0; r < 4; ++r) {
                        int token = bm + wr * 64 + m * 16 + g * 4 + r;
                        kb[(size_t)token * QKS_ + h * QKD_ + dbase + n * 16 + l15] =
                            f2bf(acc[m][n][r]);
                    }
        } else {
            u16* vtb = (u16*)Cv2;
            const int b = bm >> 11;
#pragma unroll
            for (int m = 0; m < 4; ++m)
#pragma unroll
                for (int n = 0; n < 4; ++n) {
                    const int vc = base - 2048 + n * 16 + l15;
                    const int qrow = (bm + wr * 64 + m * 16 + g * 4) & (L_ - 1);
                    u64 pk = (u64)pk2(acc[m][n][0], acc[m][n][1]) |
                             ((u64)pk2(acc[m][n][2], acc[m][n][3]) << 32);
                    *(u64*)(vtb + (size_t)(b * NHHD_ + vc) * L_ + qrow) = pk;
                }
        }
    }
}

// ------------- RoPE on k_rope (64 cols at stride S) + broadcast to all heads of k -------------
__global__ __launch_bounds__(256) void rope_k_kernel(const u16* __restrict__ src, int S,
                                                     u16* __restrict__ dst,
                                                     const float2* __restrict__ tab) {
    int idx = blockIdx.x * 256 + threadIdx.x;  // BL*32
    int token = idx >> 5, i = idx & 31;
    int pos = token & (L_ - 1);
    float2 cs = tab[pos * 32 + i];
    float x1 = bf2f(src[(size_t)token * S + i]);
    float x2 = bf2f(src[(size_t)token * S + i + 32]);
    u16 o1 = f2bf(x1 * cs.x - x2 * cs.y);
    u16 o2 = f2bf(x2 * cs.x + x1 * cs.y);
    u16* base = dst + (size_t)token * QKS_ + HD_;
#pragma unroll
    for (int h = 0; h < NH_; ++h) {
        base[h * QKD_ + i] = o1;
        base[h * QKD_ + i + 32] = o2;
    }
}

// ------------- causal flash attention: KVBLK=32, 4-way KV split, 4 blocks/CU -------------
// Structural halving of the R10 kernel: s1 deleted, QK 12 MFMA on s0, pack/PV = old c<2
// branch verbatim. V tile [128][32] (4 granules/row) -> swizzle key (row>>1)&3 (involution).
// grid (32,16,2): fid -> (b,h,p,split); qtiles p & 15-p; KV tiles t = split, split+4, ...
// (exactly 17 tiles per block). LDS 40960 B -> 4 blocks/CU = 4 waves/SIMD.
__global__ __launch_bounds__(256, 4) void flash_attn(const u16* __restrict__ q, const u16* __restrict__ k,
                                                     const u16* __restrict__ vt,
                                                     u16* __restrict__ opart, float* __restrict__ mlpart) {
    __shared__ __align__(16) u16 Ks[2][32 * 192];   // 2 x 12288 B
    __shared__ __align__(16) u16 Vs[2][128 * 32];   // 2 x 8192 B
    const int fid = blockIdx.x + 32 * blockIdx.y + 512 * blockIdx.z;  // [0,1024)
    const int xcd = fid & 7, slot = fid >> 3;                          // slot in [0,128)
    const int group = xcd * 4 + (slot >> 5);                           // [0,32): 4 (b,h) groups/XCD
    const int member = slot & 31;                                      // [0,32): (p,split)
    const int b = group >> 4, h = group & 15;
    const int p = member >> 2, split = member & 3;
    const int tid = threadIdx.x, w = tid >> 6, l = tid & 63;
    const int ql = l & 31, hi = l >> 5;
    const int sw = ql & 7;            // K-tile swizzle key (8 granules/row)
    const int swv = (ql >> 1) & 3;    // V-tile swizzle key (4 granules/row)

    const u16* kbase = k + (size_t)(b * L_) * QKS_ + h * QKD_;
    const u16* vtbase = vt + (size_t)(b * NHHD_ + h * HD_) * L_;

    // per-lane pre-swizzled global source offsets (elements within a tile)
    int koff[3], voff[2];
#pragma unroll
    for (int j = 0; j < 3; ++j) {
        int off = j * 4096 + tid * 16;       // byte offset of this lane's LDS slot in K tile
        int row = off / 384;                 // [0,32)
        int gr = (off % 384) / 16;           // [0,24)
        koff[j] = row * QKS_ + (gr ^ (row & 7)) * 8;
    }
#pragma unroll
    for (int j = 0; j < 2; ++j) {
        int off = j * 4096 + tid * 16;       // byte offset in V tile
        int row = off >> 6;                  // [0,128), 64 B rows
        int gr = (off >> 4) & 3;             // [0,4)
        voff[j] = row * L_ + (gr ^ ((row >> 1) & 3)) * 8;
    }

    auto STAGE = [&](int buf, int kv0) {
        const u16* kb = kbase + (size_t)kv0 * QKS_;
#pragma unroll
        for (int j = 0; j < 3; ++j)
            gload16(kb + koff[j], (u16*)Ks[buf] + j * 2048 + w * 512);
        const u16* vb = vtbase + kv0;
#pragma unroll
        for (int j = 0; j < 2; ++j)
            gload16(vb + voff[j], (u16*)Vs[buf] + j * 2048 + w * 512);
    };

    for (int half = 0; half < 2; ++half) {
        const int qtile = half ? 15 - p : p;
        const int q0 = qtile * 128;
        const int qabs = q0 + w * 32 + ql;

        bf16x8 qf[12];
        {
            const u16* qrow = q + (size_t)(b * L_ + qabs) * QKS_ + h * QKD_;
#pragma unroll
            for (int c = 0; c < 12; ++c) qf[c] = ld8(qrow + c * 16 + hi * 8);
        }
        f32x16 o[4];
#pragma unroll
        for (int n = 0; n < 4; ++n)
#pragma unroll
            for (int r = 0; r < 16; ++r) o[n][r] = 0.f;
        float m2 = -1e30f, lsum = 0.f;

        const int ntk = 4 * qtile + 4;       // KV tiles of 32
        __syncthreads();   // all waves done reading LDS from previous half
        STAGE(0, split * 32);
        int i = 0;
        for (int t = split; t < ntk; t += 4, ++i) {
            __syncthreads();   // tile t landed, other buf free
            if (t + 4 < ntk) STAGE((i + 1) & 1, (t + 4) * 32);
            const u16* Kb = Ks[i & 1];
            const u16* Vb = Vs[i & 1];
            const int kv0 = t * 32;

            // QK^T: S^T[kv 0..31][q], single 32-row block (scores in exp2 domain, Q pre-scaled)
            f32x16 s0;
#pragma unroll
            for (int r = 0; r < 16; ++r) s0[r] = 0.f;
#pragma unroll
            for (int c = 0; c < 12; ++c) {
                int gsw = ((2 * c + hi) ^ sw) * 16;
                bf16x8 k0 = ld8((const u16*)((const char*)Kb + ql * 384 + gsw));
                s0 = mfma32(k0, qf[c], s0);
            }

            // mask + row max
            const bool domask = (kv0 + 31 > q0);
            float mx = -3e38f;
#pragma unroll
            for (int r = 0; r < 16; ++r) {
                const int kk = (r & 3) + 8 * (r >> 2) + 4 * hi;
                float x0 = s0[r];
                if (domask && (kv0 + kk > qabs)) x0 = -3e38f;
                s0[r] = x0;
                mx = fmaxf(mx, x0);
            }
            mx = fmaxf(mx, __shfl_xor(mx, 32));

            // defer-rescale (T13)
            if (__any(mx > m2 + 8.f)) {
                const float mnew = fmaxf(m2, mx);
                const float f = exp2f(m2 - mnew);
                m2 = mnew;
                lsum *= f;
#pragma unroll
                for (int n = 0; n < 4; ++n)
#pragma unroll
                    for (int r = 0; r < 16; ++r) o[n][r] *= f;
            }

            float sl = 0.f;
#pragma unroll
            for (int r = 0; r < 16; ++r) {
                float p0 = exp2f(s0[r] - m2);
                s0[r] = p0;
                sl += p0;
            }
            lsum += sl;

            // P -> B-fragments via pack + permlane32_swap, then PV (transposed)
#pragma unroll
            for (int c = 0; c < 2; ++c) {
                const int rb = 8 * c;
                u32 a0 = pk2(s0[rb + 0], s0[rb + 1]);
                u32 a1 = pk2(s0[rb + 2], s0[rb + 3]);
                u32 b0 = pk2(s0[rb + 4], s0[rb + 5]);
                u32 b1 = pk2(s0[rb + 6], s0[rb + 7]);
                plswap(a0, b0);
                plswap(a1, b1);
                u32x4 pw = {a0, a1, b0, b1};
                bf16x8 pf = __builtin_bit_cast(bf16x8, pw);
                const int gsv = ((2 * c + hi) ^ swv) * 16;
#pragma unroll
                for (int n = 0; n < 4; ++n) {
                    bf16x8 vf = ld8((const u16*)((const char*)Vb + (32 * n + ql) * 64 + gsv));
                    o[n] = mfma32(vf, pf, o[n]);
                }
            }
        }

        // epilogue: write unnormalized partial O (bf16) + (m, l) for this split
        const float ltot = lsum + __shfl_xor(lsum, 32);
        const int row = ((b * NH_ + h) << 11) + qabs;
        u16* ob = opart + ((size_t)split * ROWS_ + row) * 128;
#pragma unroll
        for (int n = 0; n < 4; ++n)
#pragma unroll
            for (int rg = 0; rg < 4; ++rg) {
                const int d0 = 32 * n + 8 * rg + 4 * hi;
                u64 pk = (u64)pk2(o[n][4 * rg + 0], o[n][4 * rg + 1]) |
                         ((u64)pk2(o[n][4 * rg + 2], o[n][4 * rg + 3]) << 32);
                *(u64*)(ob + d0) = pk;
            }
        if (!hi) {
            float2 ml = {m2, ltot};
            *(float2*)(mlpart + ((size_t)split * ROWS_ + row) * 2) = ml;
        }
    }
}

// ------------- combine the four KV-split partials (bf16) -> attn_o (bf16) -------------
__global__ __launch_bounds__(256) void combine_attn(const u16* __restrict__ opart,
                                                    const float* __restrict__ mlpart,
                                                    u16* __restrict__ attn_o) {
    int idx = blockIdx.x * 256 + threadIdx.x;   // ROWS_*32 threads, 4 d each
    int row = idx >> 5, dq = (idx & 31) * 4;
    float2 ml[4];
    float m = -3e38f;
#pragma unroll
    for (int s = 0; s < 4; ++s) {
        ml[s] = *(const float2*)(mlpart + ((size_t)s * ROWS_ + row) * 2);
        m = fmaxf(m, ml[s].x);
    }
    float wgt[4], denom = 0.f;
#pragma unroll
    for (int s = 0; s < 4; ++s) {
        wgt[s] = exp2f(ml[s].x - m);
        denom += wgt[s] * ml[s].y;
    }
    const float inv = 1.f / denom;
    float acc0 = 0.f, acc1 = 0.f, acc2 = 0.f, acc3 = 0.f;
#pragma unroll
    for (int s = 0; s < 4; ++s) {
        u64 v = *(const u64*)(opart + ((size_t)s * ROWS_ + row) * 128 + dq);
        acc0 += bf2f((u16)v) * wgt[s];
        acc1 += bf2f((u16)(v >> 16)) * wgt[s];
        acc2 += bf2f((u16)(v >> 32)) * wgt[s];
        acc3 += bf2f((u16)(v >> 48)) * wgt[s];
    }
    int b = row >> 15, h = (row >> 11) & 15, qrow = row & 2047;
    u16* dst = attn_o + (size_t)(b * L_ + qrow) * NHHD_ + h * HD_ + dq;
    u64 pk = (u64)pk2(acc0 * inv, acc1 * inv) | ((u64)pk2(acc2 * inv, acc3 * inv) << 32);
    *(u64*)dst = pk;
}

extern "C" void kernel_launch(void* const* d_in, const int* in_sizes, int n_in,
                              void* d_out, int out_size, void* d_ws, size_t ws_size,
                              hipStream_t stream) {
    (void)in_sizes; (void)n_in; (void)out_size; (void)ws_size;
    const float* x = (const float*)d_in[0];
    const float* wq_down = (const float*)d_in[1];
    const float* wq_up = (const float*)d_in[2];
    const float* wq_rope = (const float*)d_in[3];
    const float* wkv_down = (const float*)d_in[4];
    const float* wk_up = (const float*)d_in[5];
    const float* wv_up = (const float*)d_in[6];
    const float* wk_rope = (const float*)d_in[7];
    const float* wo = (const float*)d_in[8];

    u16* W = (u16*)d_ws;
    size_t off = 0;
    auto alloc = [&](size_t e) { u16* p = W + off; off += (e + 127) & ~(size_t)127; return p; };

    u16* xb    = alloc((size_t)BL_ * H_);        // 4096 x 2048
    u16* Wdn   = alloc((size_t)1408 * H_);       // [768 qd | 512 kvd | 128 kr(pad)] x 2048
    u16* Wupq  = alloc((size_t)3072 * QR_);      // [2048 qu | 1024 qr] x 768
    u16* Wupkv = alloc((size_t)4096 * KVR_);     // [2048 ku | 2048 vu] x 512
    u16* Wo_t  = alloc((size_t)H_ * NHHD_);      // 2048 x 2048
    u16* tabm  = alloc((size_t)L_ * 32 * 4);     // 2048*32 float2 = 0.5 MB
    u16* C1    = alloc((size_t)BL_ * 1408);      // latents: q_lat | kv_lat | k_rope_raw
    u16* pad_  = alloc((size_t)28835840);        // extends C1 span for opart/mlpart alias (4 splits)
    u16* qbuf  = alloc((size_t)BL_ * QKS_);
    u16* kbuf  = alloc((size_t)BL_ * QKS_);
    u16* vt    = alloc((size_t)BL_ * NHHD_);
    u16* attn_o = alloc((size_t)BL_ * NHHD_);
    (void)pad_;

    float2* tab = (float2*)tabm;
    // attention partials alias the C1+pad span (34.6M u16 = 69.2 MB); C1 is dead by flash time.
    u16* opart    = C1;                                          // 4*65536*128 bf16 = 67.1 MB
    float* mlpart = (float*)(C1 + (size_t)4 * ROWS_ * 128);      // 4*65536*2 f32 = 2.1 MB

    // 1. x cast + ALL weight transposes (one dispatch) + rope table
    cast_bf16_kernel<<<(BL_ * H_ / 4 + 255) / 256, 256, 0, stream>>>(x, xb, BL_ * H_ / 4);
    transpose_all<<<11264, 256, 0, stream>>>(wq_down, wkv_down, wk_rope, wq_up, wq_rope,
                                             wk_up, wv_up, wo, Wdn, Wupq, Wupkv, Wo_t);
    build_rope_tab<<<L_ * 32 / 256, 256, 0, stream>>>(tab);

    // 2. projection GEMMs (gemm2/gemm3 fuse pack + rope + v-transpose in their epilogues)
    gemm_bt<0><<<dim3(1408 / 128, BL_ / 128), 256, 0, stream>>>(xb, H_, Wdn, C1, nullptr, 1408, H_, nullptr);
    gemm_bt<2><<<dim3(3072 / 128, BL_ / 128), 256, 0, stream>>>(C1, 1408, Wupq, qbuf, nullptr, 0, QR_, tab);
    gemm_bt<3><<<dim3(4096 / 128, BL_ / 128), 256, 0, stream>>>(C1 + 768, 1408, Wupkv, kbuf, vt, 0, KVR_, nullptr);

    // 3. k_rope broadcast (reads C1 k_rope cols; must finish before flash overwrites C1 alias)
    rope_k_kernel<<<BL_ * 32 / 256, 256, 0, stream>>>(C1 + 1280, 1408, kbuf, tab);

    // 4. attention: 4-way KV split (1024 balanced blocks, 4/CU, XCD-grouped), then combine
    flash_attn<<<dim3(32, NH_, B_), 256, 0, stream>>>(qbuf, kbuf, vt, opart, mlpart);
    combine_attn<<<ROWS_ * 32 / 256, 256, 0, stream>>>(opart, mlpart, attn_o);

    // 5. output projection (fp32 out)
    gemm_bt<1><<<dim3(H_ / 128, BL_ / 128), 256, 0, stream>>>(attn_o, NHHD_, Wo_t, d_out, nullptr, H_, NHHD_, nullptr);
}

// Round 12
// 295.031 us; speedup vs baseline: 1.4613x; 1.4613x over previous
//
#include <hip/hip_runtime.h>

typedef unsigned short u16;
typedef unsigned int u32;
typedef unsigned long long u64;
typedef __bf16 bf16x8 __attribute__((ext_vector_type(8)));
typedef float f32x4 __attribute__((ext_vector_type(4)));
typedef float f32x16 __attribute__((ext_vector_type(16)));
typedef u32 u32x4 __attribute__((ext_vector_type(4)));

#define DEV static __device__ __forceinline__

constexpr int B_ = 2, L_ = 2048, H_ = 2048;
constexpr int NH_ = 16, HD_ = 128, RD_ = 64;
constexpr int QR_ = 768, KVR_ = 512;
constexpr int BL_ = B_ * L_;          // 4096 tokens
constexpr int QKD_ = HD_ + RD_;       // 192
constexpr int QKS_ = NH_ * QKD_;      // 3072
constexpr int NHHD_ = NH_ * HD_;      // 2048
constexpr int ROWS_ = B_ * NH_ * L_;  // 65536 partial rows per split
constexpr float SCALE2 = 0.07216878364870322f * 1.4426950408889634f;  // 1/sqrt(192)*log2(e)

DEV u16 f2bf(float f) {            // native RNE cast; compiler fuses pairs into v_cvt_pk_bf16_f32
    __bf16 h = (__bf16)f;
    return __builtin_bit_cast(u16, h);
}
DEV float bf2f(u16 h) {
    u32 u = ((u32)h) << 16;
    return __builtin_bit_cast(float, u);
}
DEV u32 pk2(float lo, float hi) { return (u32)f2bf(lo) | ((u32)f2bf(hi) << 16); }
DEV bf16x8 ld8(const u16* p) { return __builtin_bit_cast(bf16x8, *(const u32x4*)p); }
DEV f32x4 mfma16(bf16x8 a, bf16x8 b, f32x4 c) {
    return __builtin_amdgcn_mfma_f32_16x16x32_bf16(a, b, c, 0, 0, 0);
}
DEV f32x16 mfma32(bf16x8 a, bf16x8 b, f32x16 c) {
    return __builtin_amdgcn_mfma_f32_32x32x16_bf16(a, b, c, 0, 0, 0);
}
DEV void gload16(const void* g, void* l) {
    __builtin_amdgcn_global_load_lds((const __attribute__((address_space(1))) void*)g,
                                     (__attribute__((address_space(3))) void*)l, 16, 0, 0);
}
// half-exchange: after plswap(a,b): a = {a_lo | b_lo}, b = {a_hi | b_hi} across lane halves.
// Routing HW-verified R4/R10 (passed with identical surrounding pack code).
DEV void plswap(u32& a, u32& b) {
    asm("v_permlane32_swap_b32 %0, %1" : "+v"(a), "+v"(b));
}

// ---------------- elementwise cast: f32 -> bf16, 4 elems/thread ----------------
__global__ __launch_bounds__(256) void cast_bf16_kernel(const float* __restrict__ src,
                                                        u16* __restrict__ dst, int n4) {
    int i = blockIdx.x * 256 + threadIdx.x;
    if (i >= n4) return;
    float4 v = ((const float4*)src)[i];
    u64 pk = (u64)f2bf(v.x) | ((u64)f2bf(v.y) << 16) | ((u64)f2bf(v.z) << 32) | ((u64)f2bf(v.w) << 48);
    ((u64*)dst)[i] = pk;
}

// ------------- fused cast+transpose of ALL 8 weights in one dispatch -------------
__global__ __launch_bounds__(256) void transpose_all(
    const float* __restrict__ s0, const float* __restrict__ s1, const float* __restrict__ s2,
    const float* __restrict__ s3, const float* __restrict__ s4, const float* __restrict__ s5,
    const float* __restrict__ s6, const float* __restrict__ s7,
    u16* __restrict__ Wdn, u16* __restrict__ Wupq, u16* __restrict__ Wupkv, u16* __restrict__ Wo_t) {
    int t = blockIdx.x;
    const float* src; u16* dst; int K, N, nx;
    if (t < 1536)       {            src = s0; dst = Wdn;                          K = 2048; N = 768;  nx = 24; }
    else if (t < 2560)  { t -= 1536; src = s1; dst = Wdn + (size_t)768 * 2048;     K = 2048; N = 512;  nx = 16; }
    else if (t < 2816)  { t -= 2560; src = s2; dst = Wdn + (size_t)1280 * 2048;    K = 2048; N = 64;   nx = 4;  }
    else if (t < 4352)  { t -= 2816; src = s3; dst = Wupq;                         K = 768;  N = 2048; nx = 64; }
    else if (t < 5120)  { t -= 4352; src = s4; dst = Wupq + (size_t)2048 * 768;    K = 768;  N = 1024; nx = 32; }
    else if (t < 6144)  { t -= 5120; src = s5; dst = Wupkv;                        K = 512;  N = 2048; nx = 64; }
    else if (t < 7168)  { t -= 6144; src = s6; dst = Wupkv + (size_t)2048 * 512;   K = 512;  N = 2048; nx = 64; }
    else                { t -= 7168; src = s7; dst = Wo_t;                         K = 2048; N = 2048; nx = 64; }
    const int n0 = (t % nx) * 32, k0 = (t / nx) * 32;

    __shared__ float tile[32][33];
    int tx = threadIdx.x & 31, ty = threadIdx.x >> 5;  // 32 x 8
#pragma unroll
    for (int i = 0; i < 4; ++i) {
        int kk = ty + i * 8;
        int n = n0 + tx;
        tile[kk][tx] = (n < N) ? src[(size_t)(k0 + kk) * N + n] : 0.f;
    }
    __syncthreads();
#pragma unroll
    for (int i = 0; i < 4; ++i) {
        int nn = ty + i * 8;
        dst[(size_t)(n0 + nn) * K + k0 + tx] = f2bf(tile[tx][nn]);
    }
}

// ------------- RoPE cos/sin table: tab[pos*32+i] = {cos, sin}(pos * 10000^(-i/32)) -------------
__global__ __launch_bounds__(256) void build_rope_tab(float2* __restrict__ tab) {
    int idx = blockIdx.x * 256 + threadIdx.x;  // 2048*32
    int pos = idx >> 5, i = idx & 31;
    float freq = exp2f((float)i * (-13.287712379549449f / 32.f));
    float ang = (float)pos * freq;
    tab[idx] = make_float2(cosf(ang), sinf(ang));
}

// ---------------- GEMM: C = A(M x K, lda) * Bt(N x K)^T, BK=64, global_load_lds staging ----------------
// XCD-band swizzle (R8-confirmed fid%8 round-robin).
// EPI: 0 = bf16 C, 1 = f32 C, 2 = QPACK, 3 = KVPACK.
template <int EPI>
__global__ __launch_bounds__(256, 2) void gemm_bt(const u16* __restrict__ A, int lda,
                                                  const u16* __restrict__ Bt,
                                                  void* __restrict__ Cv, void* __restrict__ Cv2,
                                                  int ldc, int K, const float2* __restrict__ tab) {
    __shared__ u16 As[128 * 64];
    __shared__ u16 Bs[128 * 64];
    const int tid = threadIdx.x;
    const int l = tid & 63, w = tid >> 6;
    const int l15 = l & 15, g = l >> 4;
    const int wr = w >> 1, wc = w & 1;
    const int NX = gridDim.x;
    const int fid = blockIdx.x + NX * blockIdx.y;
    const int G = (NX * gridDim.y) >> 3;              // blocks per XCD (grid divisible by 8)
    const int lin = (fid & 7) * G + (fid >> 3);       // xcd-contiguous row-major tile index
    const int bm = (lin / NX) * 128, bn = (lin % NX) * 128;

    const f32x4 zero = {0.f, 0.f, 0.f, 0.f};
    f32x4 acc[4][4];
#pragma unroll
    for (int m = 0; m < 4; ++m)
#pragma unroll
        for (int n = 0; n < 4; ++n) acc[m][n] = zero;

    int aoff[4], boff[4];
#pragma unroll
    for (int j = 0; j < 4; ++j) {
        int chunk = j * 256 + tid;
        int row = chunk >> 3, gr = chunk & 7;
        aoff[j] = row * lda + gr * 8;
        boff[j] = row * K + gr * 8;
    }
    const u16* Ab = A + (size_t)bm * lda;
    const u16* Bb = Bt + (size_t)bn * K;

    const int nK = K / 64;
    for (int kt = 0; kt < nK; ++kt) {
        const int ko = kt * 64;
        __syncthreads();
#pragma unroll
        for (int j = 0; j < 4; ++j) gload16(Ab + ko + aoff[j], As + j * 2048 + w * 512);
#pragma unroll
        for (int j = 0; j < 4; ++j) gload16(Bb + ko + boff[j], Bs + j * 2048 + w * 512);
        __syncthreads();
#pragma unroll
        for (int kk = 0; kk < 2; ++kk) {
            bf16x8 af[4], bfr[4];
#pragma unroll
            for (int m = 0; m < 4; ++m)
                af[m] = ld8(As + (wr * 64 + m * 16 + l15) * 64 + kk * 32 + g * 8);
#pragma unroll
            for (int n = 0; n < 4; ++n)
                bfr[n] = ld8(Bs + (wc * 64 + n * 16 + l15) * 64 + kk * 32 + g * 8);
#pragma unroll
            for (int m = 0; m < 4; ++m)
#pragma unroll
                for (int n = 0; n < 4; ++n) acc[m][n] = mfma16(af[m], bfr[n], acc[m][n]);
        }
    }

    // ---- epilogues ----
    if constexpr (EPI == 0 || EPI == 1) {
#pragma unroll
        for (int m = 0; m < 4; ++m)
#pragma unroll
            for (int n = 0; n < 4; ++n)
#pragma unroll
                for (int r = 0; r < 4; ++r) {
                    int row = bm + wr * 64 + m * 16 + g * 4 + r;
                    int col = bn + wc * 64 + n * 16 + l15;
                    if (EPI == 1)
                        ((float*)Cv)[(size_t)row * ldc + col] = acc[m][n][r];
                    else
                        ((u16*)Cv)[(size_t)row * ldc + col] = f2bf(acc[m][n][r]);
                }
    }
    if constexpr (EPI == 2) {  // QPACK: N = [2048 q_content | 1024 q_rope]; all outputs * SCALE2
        const int base = bn + wc * 64;
        u16* qb = (u16*)Cv;
        if (base < 2048) {
            const int h = base >> 7, dbase = base & 127;
#pragma unroll
            for (int m = 0; m < 4; ++m)
#pragma unroll
                for (int n = 0; n < 4; ++n)
#pragma unroll
                    for (int r = 0; r < 4; ++r) {
                        int token = bm + wr * 64 + m * 16 + g * 4 + r;
                        qb[(size_t)token * QKS_ + h * QKD_ + dbase + n * 16 + l15] =
                            f2bf(acc[m][n][r] * SCALE2);
                    }
        } else {
            const int h = (base - 2048) >> 6;
#pragma unroll
            for (int m = 0; m < 4; ++m)
#pragma unroll
                for (int r = 0; r < 4; ++r) {
                    const int token = bm + wr * 64 + m * 16 + g * 4 + r;
                    const int pos = token & (L_ - 1);
                    u16* bp = qb + (size_t)token * QKS_ + h * QKD_ + HD_;
#pragma unroll
                    for (int n = 0; n < 2; ++n) {
                        const int i = n * 16 + l15;
                        float2 cs = tab[pos * 32 + i];
                        float x1 = acc[m][n][r], x2 = acc[m][n + 2][r];
                        bp[i] = f2bf((x1 * cs.x - x2 * cs.y) * SCALE2);
                        bp[i + 32] = f2bf((x2 * cs.x + x1 * cs.y) * SCALE2);
                    }
                }
        }
    }
    if constexpr (EPI == 3) {  // KVPACK: N = [2048 k_content | 2048 v]
        const int base = bn + wc * 64;
        if (base < 2048) {
            u16* kb = (u16*)Cv;
            const int h = base >> 7, dbase = base & 127;
#pragma unroll
            for (int m = 0; m < 4; ++m)
#pragma unroll
                for (int n = 0; n < 4; ++n)
#pragma unroll
                    for (int r = 0; r < 4; ++r) {
                        int token = bm + wr * 64 + m * 16 + g * 4 + r;
                        kb[(size_t)token * QKS_ + h * QKD_ + dbase + n * 16 + l15] =
                            f2bf(acc[m][n][r]);
                    }
        } else {
            u16* vtb = (u16*)Cv2;
            const int b = bm >> 11;
#pragma unroll
            for (int m = 0; m < 4; ++m)
#pragma unroll
                for (int n = 0; n < 4; ++n) {
                    const int vc = base - 2048 + n * 16 + l15;
                    const int qrow = (bm + wr * 64 + m * 16 + g * 4) & (L_ - 1);
                    u64 pk = (u64)pk2(acc[m][n][0], acc[m][n][1]) |
                             ((u64)pk2(acc[m][n][2], acc[m][n][3]) << 32);
                    *(u64*)(vtb + (size_t)(b * NHHD_ + vc) * L_ + qrow) = pk;
                }
        }
    }
}

// ------------- RoPE on k_rope (64 cols at stride S) + broadcast to all heads of k -------------
__global__ __launch_bounds__(256) void rope_k_kernel(const u16* __restrict__ src, int S,
                                                     u16* __restrict__ dst,
                                                     const float2* __restrict__ tab) {
    int idx = blockIdx.x * 256 + threadIdx.x;  // BL*32
    int token = idx >> 5, i = idx & 31;
    int pos = token & (L_ - 1);
    float2 cs = tab[pos * 32 + i];
    float x1 = bf2f(src[(size_t)token * S + i]);
    float x2 = bf2f(src[(size_t)token * S + i + 32]);
    u16 o1 = f2bf(x1 * cs.x - x2 * cs.y);
    u16 o2 = f2bf(x2 * cs.x + x1 * cs.y);
    u16* base = dst + (size_t)token * QKS_ + HD_;
#pragma unroll
    for (int h = 0; h < NH_; ++h) {
        base[h * QKD_ + i] = o1;
        base[h * QKD_ + i + 32] = o2;
    }
}

// ------------- causal flash attention: KVBLK=32, 4-way KV split -------------
// R11 structure, but __launch_bounds__(256, 2): the (256,4) declaration capped VGPR at 64
// and spilled the accumulator (R11: VGPR=64, FETCH 563MB). At (256,2) the kernel fits
// (~110 VGPR, cap 128) and hardware occupancy is set by usage: floor(512/VGPR) waves/SIMD,
// LDS 40960 x 4 = exactly the 160 KiB pool -> up to 4 blocks/CU with zero spill.
__global__ __launch_bounds__(256, 2) void flash_attn(const u16* __restrict__ q, const u16* __restrict__ k,
                                                     const u16* __restrict__ vt,
                                                     u16* __restrict__ opart, float* __restrict__ mlpart) {
    __shared__ __align__(16) u16 Ks[2][32 * 192];   // 2 x 12288 B
    __shared__ __align__(16) u16 Vs[2][128 * 32];   // 2 x 8192 B
    const int fid = blockIdx.x + 32 * blockIdx.y + 512 * blockIdx.z;  // [0,1024)
    const int xcd = fid & 7, slot = fid >> 3;                          // slot in [0,128)
    const int group = xcd * 4 + (slot >> 5);                           // [0,32): 4 (b,h) groups/XCD
    const int member = slot & 31;                                      // [0,32): (p,split)
    const int b = group >> 4, h = group & 15;
    const int p = member >> 2, split = member & 3;
    const int tid = threadIdx.x, w = tid >> 6, l = tid & 63;
    const int ql = l & 31, hi = l >> 5;
    const int sw = ql & 7;            // K-tile swizzle key (8 granules/row)
    const int swv = (ql >> 1) & 3;    // V-tile swizzle key (4 granules/row)

    const u16* kbase = k + (size_t)(b * L_) * QKS_ + h * QKD_;
    const u16* vtbase = vt + (size_t)(b * NHHD_ + h * HD_) * L_;

    // per-lane pre-swizzled global source offsets (elements within a tile)
    int koff[3], voff[2];
#pragma unroll
    for (int j = 0; j < 3; ++j) {
        int off = j * 4096 + tid * 16;       // byte offset of this lane's LDS slot in K tile
        int row = off / 384;                 // [0,32)
        int gr = (off % 384) / 16;           // [0,24)
        koff[j] = row * QKS_ + (gr ^ (row & 7)) * 8;
    }
#pragma unroll
    for (int j = 0; j < 2; ++j) {
        int off = j * 4096 + tid * 16;       // byte offset in V tile
        int row = off >> 6;                  // [0,128), 64 B rows
        int gr = (off >> 4) & 3;             // [0,4)
        voff[j] = row * L_ + (gr ^ ((row >> 1) & 3)) * 8;
    }

    auto STAGE = [&](int buf, int kv0) {
        const u16* kb = kbase + (size_t)kv0 * QKS_;
#pragma unroll
        for (int j = 0; j < 3; ++j)
            gload16(kb + koff[j], (u16*)Ks[buf] + j * 2048 + w * 512);
        const u16* vb = vtbase + kv0;
#pragma unroll
        for (int j = 0; j < 2; ++j)
            gload16(vb + voff[j], (u16*)Vs[buf] + j * 2048 + w * 512);
    };

    for (int half = 0; half < 2; ++half) {
        const int qtile = half ? 15 - p : p;
        const int q0 = qtile * 128;
        const int qabs = q0 + w * 32 + ql;

        bf16x8 qf[12];
        {
            const u16* qrow = q + (size_t)(b * L_ + qabs) * QKS_ + h * QKD_;
#pragma unroll
            for (int c = 0; c < 12; ++c) qf[c] = ld8(qrow + c * 16 + hi * 8);
        }
        f32x16 o[4];
#pragma unroll
        for (int n = 0; n < 4; ++n)
#pragma unroll
            for (int r = 0; r < 16; ++r) o[n][r] = 0.f;
        float m2 = -1e30f, lsum = 0.f;

        const int ntk = 4 * qtile + 4;       // KV tiles of 32
        __syncthreads();   // all waves done reading LDS from previous half
        STAGE(0, split * 32);
        int i = 0;
        for (int t = split; t < ntk; t += 4, ++i) {
            __syncthreads();   // tile t landed, other buf free
            if (t + 4 < ntk) STAGE((i + 1) & 1, (t + 4) * 32);
            const u16* Kb = Ks[i & 1];
            const u16* Vb = Vs[i & 1];
            const int kv0 = t * 32;

            // QK^T: S^T[kv 0..31][q], single 32-row block (scores in exp2 domain, Q pre-scaled)
            f32x16 s0;
#pragma unroll
            for (int r = 0; r < 16; ++r) s0[r] = 0.f;
#pragma unroll
            for (int c = 0; c < 12; ++c) {
                int gsw = ((2 * c + hi) ^ sw) * 16;
                bf16x8 k0 = ld8((const u16*)((const char*)Kb + ql * 384 + gsw));
                s0 = mfma32(k0, qf[c], s0);
            }

            // mask + row max
            const bool domask = (kv0 + 31 > q0);
            float mx = -3e38f;
#pragma unroll
            for (int r = 0; r < 16; ++r) {
                const int kk = (r & 3) + 8 * (r >> 2) + 4 * hi;
                float x0 = s0[r];
                if (domask && (kv0 + kk > qabs)) x0 = -3e38f;
                s0[r] = x0;
                mx = fmaxf(mx, x0);
            }
            mx = fmaxf(mx, __shfl_xor(mx, 32));

            // defer-rescale (T13)
            if (__any(mx > m2 + 8.f)) {
                const float mnew = fmaxf(m2, mx);
                const float f = exp2f(m2 - mnew);
                m2 = mnew;
                lsum *= f;
#pragma unroll
                for (int n = 0; n < 4; ++n)
#pragma unroll
                    for (int r = 0; r < 16; ++r) o[n][r] *= f;
            }

            float sl = 0.f;
#pragma unroll
            for (int r = 0; r < 16; ++r) {
                float p0 = exp2f(s0[r] - m2);
                s0[r] = p0;
                sl += p0;
            }
            lsum += sl;

            // P -> B-fragments via pack + permlane32_swap, then PV (transposed)
#pragma unroll
            for (int c = 0; c < 2; ++c) {
                const int rb = 8 * c;
                u32 a0 = pk2(s0[rb + 0], s0[rb + 1]);
                u32 a1 = pk2(s0[rb + 2], s0[rb + 3]);
                u32 b0 = pk2(s0[rb + 4], s0[rb + 5]);
                u32 b1 = pk2(s0[rb + 6], s0[rb + 7]);
                plswap(a0, b0);
                plswap(a1, b1);
                u32x4 pw = {a0, a1, b0, b1};
                bf16x8 pf = __builtin_bit_cast(bf16x8, pw);
                const int gsv = ((2 * c + hi) ^ swv) * 16;
#pragma unroll
                for (int n = 0; n < 4; ++n) {
                    bf16x8 vf = ld8((const u16*)((const char*)Vb + (32 * n + ql) * 64 + gsv));
                    o[n] = mfma32(vf, pf, o[n]);
                }
            }
        }

        // epilogue: write unnormalized partial O (bf16) + (m, l) for this split
        const float ltot = lsum + __shfl_xor(lsum, 32);
        const int row = ((b * NH_ + h) << 11) + qabs;
        u16* ob = opart + ((size_t)split * ROWS_ + row) * 128;
#pragma unroll
        for (int n = 0; n < 4; ++n)
#pragma unroll
            for (int rg = 0; rg < 4; ++rg) {
                const int d0 = 32 * n + 8 * rg + 4 * hi;
                u64 pk = (u64)pk2(o[n][4 * rg + 0], o[n][4 * rg + 1]) |
                         ((u64)pk2(o[n][4 * rg + 2], o[n][4 * rg + 3]) << 32);
                *(u64*)(ob + d0) = pk;
            }
        if (!hi) {
            float2 ml = {m2, ltot};
            *(float2*)(mlpart + ((size_t)split * ROWS_ + row) * 2) = ml;
        }
    }
}

// ------------- combine the four KV-split partials (bf16) -> attn_o (bf16) -------------
__global__ __launch_bounds__(256) void combine_attn(const u16* __restrict__ opart,
                                                    const float* __restrict__ mlpart,
                                                    u16* __restrict__ attn_o) {
    int idx = blockIdx.x * 256 + threadIdx.x;   // ROWS_*32 threads, 4 d each
    int row = idx >> 5, dq = (idx & 31) * 4;
    float2 ml[4];
    float m = -3e38f;
#pragma unroll
    for (int s = 0; s < 4; ++s) {
        ml[s] = *(const float2*)(mlpart + ((size_t)s * ROWS_ + row) * 2);
        m = fmaxf(m, ml[s].x);
    }
    float wgt[4], denom = 0.f;
#pragma unroll
    for (int s = 0; s < 4; ++s) {
        wgt[s] = exp2f(ml[s].x - m);
        denom += wgt[s] * ml[s].y;
    }
    const float inv = 1.f / denom;
    float acc0 = 0.f, acc1 = 0.f, acc2 = 0.f, acc3 = 0.f;
#pragma unroll
    for (int s = 0; s < 4; ++s) {
        u64 v = *(const u64*)(opart + ((size_t)s * ROWS_ + row) * 128 + dq);
        acc0 += bf2f((u16)v) * wgt[s];
        acc1 += bf2f((u16)(v >> 16)) * wgt[s];
        acc2 += bf2f((u16)(v >> 32)) * wgt[s];
        acc3 += bf2f((u16)(v >> 48)) * wgt[s];
    }
    int b = row >> 15, h = (row >> 11) & 15, qrow = row & 2047;
    u16* dst = attn_o + (size_t)(b * L_ + qrow) * NHHD_ + h * HD_ + dq;
    u64 pk = (u64)pk2(acc0 * inv, acc1 * inv) | ((u64)pk2(acc2 * inv, acc3 * inv) << 32);
    *(u64*)dst = pk;
}

extern "C" void kernel_launch(void* const* d_in, const int* in_sizes, int n_in,
                              void* d_out, int out_size, void* d_ws, size_t ws_size,
                              hipStream_t stream) {
    (void)in_sizes; (void)n_in; (void)out_size; (void)ws_size;
    const float* x = (const float*)d_in[0];
    const float* wq_down = (const float*)d_in[1];
    const float* wq_up = (const float*)d_in[2];
    const float* wq_rope = (const float*)d_in[3];
    const float* wkv_down = (const float*)d_in[4];
    const float* wk_up = (const float*)d_in[5];
    const float* wv_up = (const float*)d_in[6];
    const float* wk_rope = (const float*)d_in[7];
    const float* wo = (const float*)d_in[8];

    u16* W = (u16*)d_ws;
    size_t off = 0;
    auto alloc = [&](size_t e) { u16* p = W + off; off += (e + 127) & ~(size_t)127; return p; };

    u16* xb    = alloc((size_t)BL_ * H_);        // 4096 x 2048
    u16* Wdn   = alloc((size_t)1408 * H_);       // [768 qd | 512 kvd | 128 kr(pad)] x 2048
    u16* Wupq  = alloc((size_t)3072 * QR_);      // [2048 qu | 1024 qr] x 768
    u16* Wupkv = alloc((size_t)4096 * KVR_);     // [2048 ku | 2048 vu] x 512
    u16* Wo_t  = alloc((size_t)H_ * NHHD_);      // 2048 x 2048
    u16* tabm  = alloc((size_t)L_ * 32 * 4);     // 2048*32 float2 = 0.5 MB
    u16* C1    = alloc((size_t)BL_ * 1408);      // latents: q_lat | kv_lat | k_rope_raw
    u16* pad_  = alloc((size_t)28835840);        // extends C1 span for opart/mlpart alias (4 splits)
    u16* qbuf  = alloc((size_t)BL_ * QKS_);
    u16* kbuf  = alloc((size_t)BL_ * QKS_);
    u16* vt    = alloc((size_t)BL_ * NHHD_);
    u16* attn_o = alloc((size_t)BL_ * NHHD_);
    (void)pad_;

    float2* tab = (float2*)tabm;
    // attention partials alias the C1+pad span (34.6M u16 = 69.2 MB); C1 is dead by flash time.
    u16* opart    = C1;                                          // 4*65536*128 bf16 = 67.1 MB
    float* mlpart = (float*)(C1 + (size_t)4 * ROWS_ * 128);      // 4*65536*2 f32 = 2.1 MB

    // 1. x cast + ALL weight transposes (one dispatch) + rope table
    cast_bf16_kernel<<<(BL_ * H_ / 4 + 255) / 256, 256, 0, stream>>>(x, xb, BL_ * H_ / 4);
    transpose_all<<<11264, 256, 0, stream>>>(wq_down, wkv_down, wk_rope, wq_up, wq_rope,
                                             wk_up, wv_up, wo, Wdn, Wupq, Wupkv, Wo_t);
    build_rope_tab<<<L_ * 32 / 256, 256, 0, stream>>>(tab);

    // 2. projection GEMMs (gemm2/gemm3 fuse pack + rope + v-transpose in their epilogues)
    gemm_bt<0><<<dim3(1408 / 128, BL_ / 128), 256, 0, stream>>>(xb, H_, Wdn, C1, nullptr, 1408, H_, nullptr);
    gemm_bt<2><<<dim3(3072 / 128, BL_ / 128), 256, 0, stream>>>(C1, 1408, Wupq, qbuf, nullptr, 0, QR_, tab);
    gemm_bt<3><<<dim3(4096 / 128, BL_ / 128), 256, 0, stream>>>(C1 + 768, 1408, Wupkv, kbuf, vt, 0, KVR_, nullptr);

    // 3. k_rope broadcast (reads C1 k_rope cols; must finish before flash overwrites C1 alias)
    rope_k_kernel<<<BL_ * 32 / 256, 256, 0, stream>>>(C1 + 1280, 1408, kbuf, tab);

    // 4. attention: 4-way KV split (1024 balanced blocks, up to 4/CU, XCD-grouped), then combine
    flash_attn<<<dim3(32, NH_, B_), 256, 0, stream>>>(qbuf, kbuf, vt, opart, mlpart);
    combine_attn<<<ROWS_ * 32 / 256, 256, 0, stream>>>(opart, mlpart, attn_o);

    // 5. output projection (fp32 out)
    gemm_bt<1><<<dim3(H_ / 128, BL_ / 128), 256, 0, stream>>>(attn_o, NHHD_, Wo_t, d_out, nullptr, H_, NHHD_, nullptr);
}

// Round 13
// 271.452 us; speedup vs baseline: 1.5882x; 1.0869x over previous
//
#include <hip/hip_runtime.h>

typedef unsigned short u16;
typedef unsigned int u32;
typedef unsigned long long u64;
typedef __bf16 bf16x8 __attribute__((ext_vector_type(8)));
typedef float f32x4 __attribute__((ext_vector_type(4)));
typedef float f32x16 __attribute__((ext_vector_type(16)));
typedef u32 u32x4 __attribute__((ext_vector_type(4)));

#define DEV static __device__ __forceinline__

constexpr int B_ = 2, L_ = 2048, H_ = 2048;
constexpr int NH_ = 16, HD_ = 128, RD_ = 64;
constexpr int QR_ = 768, KVR_ = 512;
constexpr int BL_ = B_ * L_;          // 4096 tokens
constexpr int QKD_ = HD_ + RD_;       // 192
constexpr int QKS_ = NH_ * QKD_;      // 3072
constexpr int NHHD_ = NH_ * HD_;      // 2048
constexpr int ROWS_ = B_ * NH_ * L_;  // 65536 partial rows per split
constexpr float SCALE2 = 0.07216878364870322f * 1.4426950408889634f;  // 1/sqrt(192)*log2(e)

DEV u16 f2bf(float f) {            // native RNE cast; compiler fuses pairs into v_cvt_pk_bf16_f32
    __bf16 h = (__bf16)f;
    return __builtin_bit_cast(u16, h);
}
DEV float bf2f(u16 h) {
    u32 u = ((u32)h) << 16;
    return __builtin_bit_cast(float, u);
}
DEV u32 pk2(float lo, float hi) { return (u32)f2bf(lo) | ((u32)f2bf(hi) << 16); }
DEV bf16x8 ld8(const u16* p) { return __builtin_bit_cast(bf16x8, *(const u32x4*)p); }
DEV f32x4 mfma16(bf16x8 a, bf16x8 b, f32x4 c) {
    return __builtin_amdgcn_mfma_f32_16x16x32_bf16(a, b, c, 0, 0, 0);
}
DEV f32x16 mfma32(bf16x8 a, bf16x8 b, f32x16 c) {
    return __builtin_amdgcn_mfma_f32_32x32x16_bf16(a, b, c, 0, 0, 0);
}
DEV void gload16(const void* g, void* l) {
    __builtin_amdgcn_global_load_lds((const __attribute__((address_space(1))) void*)g,
                                     (__attribute__((address_space(3))) void*)l, 16, 0, 0);
}
// half-exchange: after plswap(a,b): a = {a_lo | b_lo}, b = {a_hi | b_hi} across lane halves.
// Routing HW-verified R4/R10 (passed with identical surrounding pack code).
DEV void plswap(u32& a, u32& b) {
    asm("v_permlane32_swap_b32 %0, %1" : "+v"(a), "+v"(b));
}

// ---------------- elementwise cast: f32 -> bf16, 4 elems/thread ----------------
__global__ __launch_bounds__(256) void cast_bf16_kernel(const float* __restrict__ src,
                                                        u16* __restrict__ dst, int n4) {
    int i = blockIdx.x * 256 + threadIdx.x;
    if (i >= n4) return;
    float4 v = ((const float4*)src)[i];
    u64 pk = (u64)f2bf(v.x) | ((u64)f2bf(v.y) << 16) | ((u64)f2bf(v.z) << 32) | ((u64)f2bf(v.w) << 48);
    ((u64*)dst)[i] = pk;
}

// ------------- fused cast+transpose of ALL 8 weights in one dispatch -------------
__global__ __launch_bounds__(256) void transpose_all(
    const float* __restrict__ s0, const float* __restrict__ s1, const float* __restrict__ s2,
    const float* __restrict__ s3, const float* __restrict__ s4, const float* __restrict__ s5,
    const float* __restrict__ s6, const float* __restrict__ s7,
    u16* __restrict__ Wdn, u16* __restrict__ Wupq, u16* __restrict__ Wupkv, u16* __restrict__ Wo_t) {
    int t = blockIdx.x;
    const float* src; u16* dst; int K, N, nx;
    if (t < 1536)       {            src = s0; dst = Wdn;                          K = 2048; N = 768;  nx = 24; }
    else if (t < 2560)  { t -= 1536; src = s1; dst = Wdn + (size_t)768 * 2048;     K = 2048; N = 512;  nx = 16; }
    else if (t < 2816)  { t -= 2560; src = s2; dst = Wdn + (size_t)1280 * 2048;    K = 2048; N = 64;   nx = 4;  }
    else if (t < 4352)  { t -= 2816; src = s3; dst = Wupq;                         K = 768;  N = 2048; nx = 64; }
    else if (t < 5120)  { t -= 4352; src = s4; dst = Wupq + (size_t)2048 * 768;    K = 768;  N = 1024; nx = 32; }
    else if (t < 6144)  { t -= 5120; src = s5; dst = Wupkv;                        K = 512;  N = 2048; nx = 64; }
    else if (t < 7168)  { t -= 6144; src = s6; dst = Wupkv + (size_t)2048 * 512;   K = 512;  N = 2048; nx = 64; }
    else                { t -= 7168; src = s7; dst = Wo_t;                         K = 2048; N = 2048; nx = 64; }
    const int n0 = (t % nx) * 32, k0 = (t / nx) * 32;

    __shared__ float tile[32][33];
    int tx = threadIdx.x & 31, ty = threadIdx.x >> 5;  // 32 x 8
#pragma unroll
    for (int i = 0; i < 4; ++i) {
        int kk = ty + i * 8;
        int n = n0 + tx;
        tile[kk][tx] = (n < N) ? src[(size_t)(k0 + kk) * N + n] : 0.f;
    }
    __syncthreads();
#pragma unroll
    for (int i = 0; i < 4; ++i) {
        int nn = ty + i * 8;
        dst[(size_t)(n0 + nn) * K + k0 + tx] = f2bf(tile[tx][nn]);
    }
}

// ------------- RoPE cos/sin table: tab[pos*32+i] = {cos, sin}(pos * 10000^(-i/32)) -------------
__global__ __launch_bounds__(256) void build_rope_tab(float2* __restrict__ tab) {
    int idx = blockIdx.x * 256 + threadIdx.x;  // 2048*32
    int pos = idx >> 5, i = idx & 31;
    float freq = exp2f((float)i * (-13.287712379549449f / 32.f));
    float ang = (float)pos * freq;
    tab[idx] = make_float2(cosf(ang), sinf(ang));
}

// ---------------- GEMM: C = A(M x K, lda) * Bt(N x K)^T, BK=64, global_load_lds staging ----------------
// XCD-band swizzle (R8-confirmed fid%8 round-robin).
// EPI: 0 = bf16 C, 1 = f32 C, 2 = QPACK, 3 = KVPACK.
template <int EPI>
__global__ __launch_bounds__(256, 2) void gemm_bt(const u16* __restrict__ A, int lda,
                                                  const u16* __restrict__ Bt,
                                                  void* __restrict__ Cv, void* __restrict__ Cv2,
                                                  int ldc, int K, const float2* __restrict__ tab) {
    __shared__ u16 As[128 * 64];
    __shared__ u16 Bs[128 * 64];
    const int tid = threadIdx.x;
    const int l = tid & 63, w = tid >> 6;
    const int l15 = l & 15, g = l >> 4;
    const int wr = w >> 1, wc = w & 1;
    const int NX = gridDim.x;
    const int fid = blockIdx.x + NX * blockIdx.y;
    const int G = (NX * gridDim.y) >> 3;              // blocks per XCD (grid divisible by 8)
    const int lin = (fid & 7) * G + (fid >> 3);       // xcd-contiguous row-major tile index
    const int bm = (lin / NX) * 128, bn = (lin % NX) * 128;

    const f32x4 zero = {0.f, 0.f, 0.f, 0.f};
    f32x4 acc[4][4];
#pragma unroll
    for (int m = 0; m < 4; ++m)
#pragma unroll
        for (int n = 0; n < 4; ++n) acc[m][n] = zero;

    int aoff[4], boff[4];
#pragma unroll
    for (int j = 0; j < 4; ++j) {
        int chunk = j * 256 + tid;
        int row = chunk >> 3, gr = chunk & 7;
        aoff[j] = row * lda + gr * 8;
        boff[j] = row * K + gr * 8;
    }
    const u16* Ab = A + (size_t)bm * lda;
    const u16* Bb = Bt + (size_t)bn * K;

    const int nK = K / 64;
    for (int kt = 0; kt < nK; ++kt) {
        const int ko = kt * 64;
        __syncthreads();
#pragma unroll
        for (int j = 0; j < 4; ++j) gload16(Ab + ko + aoff[j], As + j * 2048 + w * 512);
#pragma unroll
        for (int j = 0; j < 4; ++j) gload16(Bb + ko + boff[j], Bs + j * 2048 + w * 512);
        __syncthreads();
#pragma unroll
        for (int kk = 0; kk < 2; ++kk) {
            bf16x8 af[4], bfr[4];
#pragma unroll
            for (int m = 0; m < 4; ++m)
                af[m] = ld8(As + (wr * 64 + m * 16 + l15) * 64 + kk * 32 + g * 8);
#pragma unroll
            for (int n = 0; n < 4; ++n)
                bfr[n] = ld8(Bs + (wc * 64 + n * 16 + l15) * 64 + kk * 32 + g * 8);
#pragma unroll
            for (int m = 0; m < 4; ++m)
#pragma unroll
                for (int n = 0; n < 4; ++n) acc[m][n] = mfma16(af[m], bfr[n], acc[m][n]);
        }
    }

    // ---- epilogues ----
    if constexpr (EPI == 0 || EPI == 1) {
#pragma unroll
        for (int m = 0; m < 4; ++m)
#pragma unroll
            for (int n = 0; n < 4; ++n)
#pragma unroll
                for (int r = 0; r < 4; ++r) {
                    int row = bm + wr * 64 + m * 16 + g * 4 + r;
                    int col = bn + wc * 64 + n * 16 + l15;
                    if (EPI == 1)
                        ((float*)Cv)[(size_t)row * ldc + col] = acc[m][n][r];
                    else
                        ((u16*)Cv)[(size_t)row * ldc + col] = f2bf(acc[m][n][r]);
                }
    }
    if constexpr (EPI == 2) {  // QPACK: N = [2048 q_content | 1024 q_rope]; all outputs * SCALE2
        const int base = bn + wc * 64;
        u16* qb = (u16*)Cv;
        if (base < 2048) {
            const int h = base >> 7, dbase = base & 127;
#pragma unroll
            for (int m = 0; m < 4; ++m)
#pragma unroll
                for (int n = 0; n < 4; ++n)
#pragma unroll
                    for (int r = 0; r < 4; ++r) {
                        int token = bm + wr * 64 + m * 16 + g * 4 + r;
                        qb[(size_t)token * QKS_ + h * QKD_ + dbase + n * 16 + l15] =
                            f2bf(acc[m][n][r] * SCALE2);
                    }
        } else {
            const int h = (base - 2048) >> 6;
#pragma unroll
            for (int m = 0; m < 4; ++m)
#pragma unroll
                for (int r = 0; r < 4; ++r) {
                    const int token = bm + wr * 64 + m * 16 + g * 4 + r;
                    const int pos = token & (L_ - 1);
                    u16* bp = qb + (size_t)token * QKS_ + h * QKD_ + HD_;
#pragma unroll
                    for (int n = 0; n < 2; ++n) {
                        const int i = n * 16 + l15;
                        float2 cs = tab[pos * 32 + i];
                        float x1 = acc[m][n][r], x2 = acc[m][n + 2][r];
                        bp[i] = f2bf((x1 * cs.x - x2 * cs.y) * SCALE2);
                        bp[i + 32] = f2bf((x2 * cs.x + x1 * cs.y) * SCALE2);
                    }
                }
        }
    }
    if constexpr (EPI == 3) {  // KVPACK: N = [2048 k_content | 2048 v]
        const int base = bn + wc * 64;
        if (base < 2048) {
            u16* kb = (u16*)Cv;
            const int h = base >> 7, dbase = base & 127;
#pragma unroll
            for (int m = 0; m < 4; ++m)
#pragma unroll
                for (int n = 0; n < 4; ++n)
#pragma unroll
                    for (int r = 0; r < 4; ++r) {
                        int token = bm + wr * 64 + m * 16 + g * 4 + r;
                        kb[(size_t)token * QKS_ + h * QKD_ + dbase + n * 16 + l15] =
                            f2bf(acc[m][n][r]);
                    }
        } else {
            u16* vtb = (u16*)Cv2;
            const int b = bm >> 11;
#pragma unroll
            for (int m = 0; m < 4; ++m)
#pragma unroll
                for (int n = 0; n < 4; ++n) {
                    const int vc = base - 2048 + n * 16 + l15;
                    const int qrow = (bm + wr * 64 + m * 16 + g * 4) & (L_ - 1);
                    u64 pk = (u64)pk2(acc[m][n][0], acc[m][n][1]) |
                             ((u64)pk2(acc[m][n][2], acc[m][n][3]) << 32);
                    *(u64*)(vtb + (size_t)(b * NHHD_ + vc) * L_ + qrow) = pk;
                }
        }
    }
}

// ------------- RoPE on k_rope (64 cols at stride S) + broadcast to all heads of k -------------
__global__ __launch_bounds__(256) void rope_k_kernel(const u16* __restrict__ src, int S,
                                                     u16* __restrict__ dst,
                                                     const float2* __restrict__ tab) {
    int idx = blockIdx.x * 256 + threadIdx.x;  // BL*32
    int token = idx >> 5, i = idx & 31;
    int pos = token & (L_ - 1);
    float2 cs = tab[pos * 32 + i];
    float x1 = bf2f(src[(size_t)token * S + i]);
    float x2 = bf2f(src[(size_t)token * S + i + 32]);
    u16 o1 = f2bf(x1 * cs.x - x2 * cs.y);
    u16 o2 = f2bf(x2 * cs.x + x1 * cs.y);
    u16* base = dst + (size_t)token * QKS_ + HD_;
#pragma unroll
    for (int h = 0; h < NH_; ++h) {
        base[h * QKD_ + i] = o1;
        base[h * QKD_ + i + 32] = o2;
    }
}

// ------------- causal flash attention, swapped-QK 32x32, paired qtiles, KV-parity split -------------
// R10 best-known configuration (reverted from the KVBLK=32 experiments, R11/R12 both worse):
// KVBLK=64, 2-way split, launch_bounds(256,2), LDS 81920 (2 blocks/CU), plswap pack,
// bf16 partials, defer-rescale (T13), XCD-group swizzle (R8).
__global__ __launch_bounds__(256, 2) void flash_attn(const u16* __restrict__ q, const u16* __restrict__ k,
                                                     const u16* __restrict__ vt,
                                                     u16* __restrict__ opart, float* __restrict__ mlpart) {
    __shared__ __align__(16) u16 Ks[2][64 * 192];   // 2 x 24576 B
    __shared__ __align__(16) u16 Vs[2][128 * 64];   // 2 x 16384 B
    const int fid = blockIdx.x + 16 * blockIdx.y + 256 * blockIdx.z;  // [0,512)
    const int xcd = fid & 7, slot = fid >> 3;                          // strict round-robin model
    const int group = xcd * 4 + (slot >> 4);                           // [0,32): 4 (b,h) groups/XCD
    const int member = slot & 15;                                      // [0,16): (p,split)
    const int b = group >> 4, h = group & 15;
    const int p = member >> 1, split = member & 1;
    const int tid = threadIdx.x, w = tid >> 6, l = tid & 63;
    const int ql = l & 31, hi = l >> 5;
    const int sw = ql & 7;

    const u16* kbase = k + (size_t)(b * L_) * QKS_ + h * QKD_;
    const u16* vtbase = vt + (size_t)(b * NHHD_ + h * HD_) * L_;

    int koff[6], voff[4];
#pragma unroll
    for (int j = 0; j < 6; ++j) {
        int off = j * 4096 + tid * 16;
        int row = off / 384;
        int gr = (off % 384) / 16;
        koff[j] = row * QKS_ + (gr ^ (row & 7)) * 8;
    }
#pragma unroll
    for (int j = 0; j < 4; ++j) {
        int off = j * 4096 + tid * 16;
        int row = off >> 7;
        int gr = (off >> 4) & 7;
        voff[j] = row * L_ + (gr ^ (row & 7)) * 8;
    }

    auto STAGE = [&](int buf, int kv0) {
        const u16* kb = kbase + (size_t)kv0 * QKS_;
#pragma unroll
        for (int j = 0; j < 6; ++j)
            gload16(kb + koff[j], (u16*)Ks[buf] + j * 2048 + w * 512);
        const u16* vb = vtbase + kv0;
#pragma unroll
        for (int j = 0; j < 4; ++j)
            gload16(vb + voff[j], (u16*)Vs[buf] + j * 2048 + w * 512);
    };

    for (int half = 0; half < 2; ++half) {
        const int qtile = half ? 15 - p : p;
        const int q0 = qtile * 128;
        const int qabs = q0 + w * 32 + ql;

        bf16x8 qf[12];
        {
            const u16* qrow = q + (size_t)(b * L_ + qabs) * QKS_ + h * QKD_;
#pragma unroll
            for (int c = 0; c < 12; ++c) qf[c] = ld8(qrow + c * 16 + hi * 8);
        }
        f32x16 o[4];
#pragma unroll
        for (int n = 0; n < 4; ++n)
#pragma unroll
            for (int r = 0; r < 16; ++r) o[n][r] = 0.f;
        float m2 = -1e30f, lsum = 0.f;

        const int nt = 2 * qtile + 2;
        __syncthreads();   // all waves done reading LDS from previous half
        STAGE(0, split * 64);
        int i = 0;
        for (int t = split; t < nt; t += 2, ++i) {
            __syncthreads();   // tile t landed, other buf free
            if (t + 2 < nt) STAGE((i + 1) & 1, (t + 2) * 64);
            const u16* Kb = Ks[i & 1];
            const u16* Vb = Vs[i & 1];
            const int kv0 = t * 64;

            // QK^T: S^T[kv][q], two 32-row halves (scores already in exp2 domain via pre-scaled Q)
            f32x16 s0, s1;
#pragma unroll
            for (int r = 0; r < 16; ++r) { s0[r] = 0.f; s1[r] = 0.f; }
#pragma unroll
            for (int c = 0; c < 12; ++c) {
                int gsw = ((2 * c + hi) ^ sw) * 16;
                bf16x8 k0 = ld8((const u16*)((const char*)Kb + ql * 384 + gsw));
                bf16x8 k1 = ld8((const u16*)((const char*)Kb + (32 + ql) * 384 + gsw));
                s0 = mfma32(k0, qf[c], s0);
                s1 = mfma32(k1, qf[c], s1);
            }

            // softmax (exp2 domain), lane-local + one cross-half exchange
            const bool domask = (kv0 + 63 > q0);
            float mx = -3e38f;
#pragma unroll
            for (int r = 0; r < 16; ++r) {
                const int kk = (r & 3) + 8 * (r >> 2) + 4 * hi;
                float x0 = s0[r];
                float x1 = s1[r];
                if (domask) {
                    if (kv0 + kk > qabs) x0 = -3e38f;
                    if (kv0 + 32 + kk > qabs) x1 = -3e38f;
                }
                s0[r] = x0; s1[r] = x1;
                mx = fmaxf(mx, fmaxf(x0, x1));
            }
            mx = fmaxf(mx, __shfl_xor(mx, 32));

            // defer-rescale (T13): rescale only when the running max grew materially.
            if (__any(mx > m2 + 8.f)) {
                const float mnew = fmaxf(m2, mx);
                const float f = exp2f(m2 - mnew);
                m2 = mnew;
                lsum *= f;
#pragma unroll
                for (int n = 0; n < 4; ++n)
#pragma unroll
                    for (int r = 0; r < 16; ++r) o[n][r] *= f;
            }

            float sl = 0.f;
#pragma unroll
            for (int r = 0; r < 16; ++r) {
                float p0 = exp2f(s0[r] - m2);
                float p1 = exp2f(s1[r] - m2);
                s0[r] = p0; s1[r] = p1;
                sl += p0 + p1;
            }
            lsum += sl;

            // P -> B-fragments via pack + permlane32_swap half-exchange, then PV (transposed)
#pragma unroll
            for (int c = 0; c < 4; ++c) {
                const int rb = 8 * (c & 1);
                float p0, p1, p2, p3, p4, p5, p6, p7;
                if (c < 2) {
                    p0 = s0[rb + 0]; p1 = s0[rb + 1]; p2 = s0[rb + 2]; p3 = s0[rb + 3];
                    p4 = s0[rb + 4]; p5 = s0[rb + 5]; p6 = s0[rb + 6]; p7 = s0[rb + 7];
                } else {
                    p0 = s1[rb + 0]; p1 = s1[rb + 1]; p2 = s1[rb + 2]; p3 = s1[rb + 3];
                    p4 = s1[rb + 4]; p5 = s1[rb + 5]; p6 = s1[rb + 6]; p7 = s1[rb + 7];
                }
                u32 a0 = pk2(p0, p1), a1 = pk2(p2, p3);
                u32 b0 = pk2(p4, p5), b1 = pk2(p6, p7);
                plswap(a0, b0);
                plswap(a1, b1);
                u32x4 pw = {a0, a1, b0, b1};
                bf16x8 pf = __builtin_bit_cast(bf16x8, pw);
                const int gsw = ((2 * c + hi) ^ sw) * 16;
#pragma unroll
                for (int n = 0; n < 4; ++n) {
                    bf16x8 vf = ld8((const u16*)((const char*)Vb + (32 * n + ql) * 128 + gsw));
                    o[n] = mfma32(vf, pf, o[n]);
                }
            }
        }

        // epilogue: write unnormalized partial O (bf16) + (m, l) for this split
        const float ltot = lsum + __shfl_xor(lsum, 32);
        const int row = ((b * NH_ + h) << 11) + qabs;
        u16* ob = opart + ((size_t)split * ROWS_ + row) * 128;
#pragma unroll
        for (int n = 0; n < 4; ++n)
#pragma unroll
            for (int rg = 0; rg < 4; ++rg) {
                const int d0 = 32 * n + 8 * rg + 4 * hi;
                u64 pk = (u64)pk2(o[n][4 * rg + 0], o[n][4 * rg + 1]) |
                         ((u64)pk2(o[n][4 * rg + 2], o[n][4 * rg + 3]) << 32);
                *(u64*)(ob + d0) = pk;
            }
        if (!hi) {
            float2 ml = {m2, ltot};
            *(float2*)(mlpart + ((size_t)split * ROWS_ + row) * 2) = ml;
        }
    }
}

// ------------- combine the two KV-split partials (bf16) -> attn_o (bf16) -------------
__global__ __launch_bounds__(256) void combine_attn(const u16* __restrict__ opart,
                                                    const float* __restrict__ mlpart,
                                                    u16* __restrict__ attn_o) {
    int idx = blockIdx.x * 256 + threadIdx.x;   // ROWS_*32 threads, 4 d each
    int row = idx >> 5, dq = (idx & 31) * 4;
    float2 ml0 = *(const float2*)(mlpart + (size_t)row * 2);
    float2 ml1 = *(const float2*)(mlpart + ((size_t)ROWS_ + row) * 2);
    float m = fmaxf(ml0.x, ml1.x);
    float w0 = exp2f(ml0.x - m), w1 = exp2f(ml1.x - m);
    float inv = 1.f / (w0 * ml0.y + w1 * ml1.y);
    w0 *= inv; w1 *= inv;
    u64 av = *(const u64*)(opart + (size_t)row * 128 + dq);
    u64 cv = *(const u64*)(opart + ((size_t)ROWS_ + row) * 128 + dq);
    float a0 = bf2f((u16)av), a1 = bf2f((u16)(av >> 16));
    float a2 = bf2f((u16)(av >> 32)), a3 = bf2f((u16)(av >> 48));
    float c0 = bf2f((u16)cv), c1 = bf2f((u16)(cv >> 16));
    float c2 = bf2f((u16)(cv >> 32)), c3 = bf2f((u16)(cv >> 48));
    int b = row >> 15, h = (row >> 11) & 15, qrow = row & 2047;
    u16* dst = attn_o + (size_t)(b * L_ + qrow) * NHHD_ + h * HD_ + dq;
    u64 pk = (u64)pk2(a0 * w0 + c0 * w1, a1 * w0 + c1 * w1) |
             ((u64)pk2(a2 * w0 + c2 * w1, a3 * w0 + c3 * w1) << 32);
    *(u64*)dst = pk;
}

extern "C" void kernel_launch(void* const* d_in, const int* in_sizes, int n_in,
                              void* d_out, int out_size, void* d_ws, size_t ws_size,
                              hipStream_t stream) {
    (void)in_sizes; (void)n_in; (void)out_size; (void)ws_size;
    const float* x = (const float*)d_in[0];
    const float* wq_down = (const float*)d_in[1];
    const float* wq_up = (const float*)d_in[2];
    const float* wq_rope = (const float*)d_in[3];
    const float* wkv_down = (const float*)d_in[4];
    const float* wk_up = (const float*)d_in[5];
    const float* wv_up = (const float*)d_in[6];
    const float* wk_rope = (const float*)d_in[7];
    const float* wo = (const float*)d_in[8];

    u16* W = (u16*)d_ws;
    size_t off = 0;
    auto alloc = [&](size_t e) { u16* p = W + off; off += (e + 127) & ~(size_t)127; return p; };

    u16* xb    = alloc((size_t)BL_ * H_);        // 4096 x 2048
    u16* Wdn   = alloc((size_t)1408 * H_);       // [768 qd | 512 kvd | 128 kr(pad)] x 2048
    u16* Wupq  = alloc((size_t)3072 * QR_);      // [2048 qu | 1024 qr] x 768
    u16* Wupkv = alloc((size_t)4096 * KVR_);     // [2048 ku | 2048 vu] x 512
    u16* Wo_t  = alloc((size_t)H_ * NHHD_);      // 2048 x 2048
    u16* tabm  = alloc((size_t)L_ * 32 * 4);     // 2048*32 float2 = 0.5 MB
    u16* C1    = alloc((size_t)BL_ * 1408);      // latents: q_lat | kv_lat | k_rope_raw
    u16* pad_  = alloc((size_t)28311552);        // extends C1 span for opart/mlpart alias
    u16* qbuf  = alloc((size_t)BL_ * QKS_);
    u16* kbuf  = alloc((size_t)BL_ * QKS_);
    u16* vt    = alloc((size_t)BL_ * NHHD_);
    u16* attn_o = alloc((size_t)BL_ * NHHD_);
    (void)pad_;

    float2* tab = (float2*)tabm;
    // attention partials alias the C1+pad span; C1 is dead by flash time.
    u16* opart    = C1;                                          // 2*65536*128 bf16 = 33.5 MB
    float* mlpart = (float*)(C1 + (size_t)2 * ROWS_ * 128);      // 2*65536*2 f32 = 1.05 MB

    // 1. x cast + ALL weight transposes (one dispatch) + rope table
    cast_bf16_kernel<<<(BL_ * H_ / 4 + 255) / 256, 256, 0, stream>>>(x, xb, BL_ * H_ / 4);
    transpose_all<<<11264, 256, 0, stream>>>(wq_down, wkv_down, wk_rope, wq_up, wq_rope,
                                             wk_up, wv_up, wo, Wdn, Wupq, Wupkv, Wo_t);
    build_rope_tab<<<L_ * 32 / 256, 256, 0, stream>>>(tab);

    // 2. projection GEMMs (gemm2/gemm3 fuse pack + rope + v-transpose in their epilogues)
    gemm_bt<0><<<dim3(1408 / 128, BL_ / 128), 256, 0, stream>>>(xb, H_, Wdn, C1, nullptr, 1408, H_, nullptr);
    gemm_bt<2><<<dim3(3072 / 128, BL_ / 128), 256, 0, stream>>>(C1, 1408, Wupq, qbuf, nullptr, 0, QR_, tab);
    gemm_bt<3><<<dim3(4096 / 128, BL_ / 128), 256, 0, stream>>>(C1 + 768, 1408, Wupkv, kbuf, vt, 0, KVR_, nullptr);

    // 3. k_rope broadcast (reads C1 k_rope cols; must finish before flash overwrites C1 alias)
    rope_k_kernel<<<BL_ * 32 / 256, 256, 0, stream>>>(C1 + 1280, 1408, kbuf, tab);

    // 4. attention: KV-parity split (512 balanced blocks, 2/CU, XCD-grouped), then combine
    flash_attn<<<dim3(16, NH_, B_), 256, 0, stream>>>(qbuf, kbuf, vt, opart, mlpart);
    combine_attn<<<ROWS_ * 32 / 256, 256, 0, stream>>>(opart, mlpart, attn_o);

    // 5. output projection (fp32 out)
    gemm_bt<1><<<dim3(H_ / 128, BL_ / 128), 256, 0, stream>>>(attn_o, NHHD_, Wo_t, d_out, nullptr, H_, NHHD_, nullptr);
}